// Round 6
// baseline (174.738 us; speedup 1.0000x reference)
//
#include <hip/hip_runtime.h>

// SpatialDistangleLoss: loss = sum_p |y_p| * (box5x5(|y|)_p - |y_p|) / 25 / (H*W*B)
// y shape (8, 320, 96, 96) fp32 -> 2560 planes of 96x96.
//
// R6: no LDS, no barrier. Each lane owns 8 columns x 12 output rows; loads its
// own 32B per row (coalesced, 16 fully-unrolled independent iters -> deep MLP);
// horizontal 5-sum halo (2 cols each side) comes from neighbor lanes via
// __shfl (ds_permute, no LDS storage, no sync). Vertical 5-sum is a register
// ring. 12 lanes per (plane,strip) unit, 5 units per wave (60/64 lanes active).
// R3/R5 showed the LDS stage->barrier->reread round-trip pinned us at ~2.9TB/s;
// this removes it. Reduction stays atomic-free (R2: same-address atomic chain
// serializes at ~40ns/block).

#define HH 96
#define WW 96
#define NPLANES 2560
#define RSTRIP 12
#define STRIPS (HH / RSTRIP)      // 8
#define UNITS (NPLANES * STRIPS)  // 20480 (plane,strip) work units
#define UPW 5                     // units per wave (12 lanes each, 60/64 lanes)
#define NWAVES (UNITS / UPW)      // 4096
#define NBLOCKS (NWAVES / 4)      // 1024 blocks of 256
#define SCALE (1.0f / (25.0f * 96.0f * 96.0f * 8.0f))

__global__ __launch_bounds__(256, 4) void sdl_partial(const float* __restrict__ y,
                                                      float* __restrict__ ws) {
    const int tid  = threadIdx.x;
    const int lane = tid & 63;
    const int wid  = tid >> 6;
    const int wgid = blockIdx.x * 4 + wid;

    const int sub = lane / 12;   // 0..4 active, 5 = idle (lanes 60..63)
    const int c8  = lane % 12;   // col-group of 8: cols c8*8 .. c8*8+7
    const bool active = (sub < UPW);
    const int unit  = wgid * UPW + (active ? sub : 0);  // clamp idle lanes to a valid unit
    const int plane = unit / STRIPS;
    const int strip = unit % STRIPS;
    const int row0  = strip * RSTRIP;

    const float* base = y + (size_t)plane * (HH * WW) + c8 * 8;
    const bool hl = (c8 > 0);
    const bool hr = (c8 < 11);

    float rs[5][8];  // ring: horizontal 5-sums for the last 5 loaded rows
    float av[3][8];  // ring: center |y| for the last 3 loaded rows
#pragma unroll
    for (int k = 0; k < 5; ++k)
#pragma unroll
        for (int j = 0; j < 8; ++j) rs[k][j] = 0.0f;
#pragma unroll
    for (int k = 0; k < 3; ++k)
#pragma unroll
        for (int j = 0; j < 8; ++j) av[k][j] = 0.0f;

    float acc = 0.0f;

#pragma unroll
    for (int i = 0; i < RSTRIP + 4; ++i) {
        const int r = row0 - 2 + i;  // row being loaded
        float x[8];
        if ((unsigned)r < (unsigned)HH) {
            float4 a = *(const float4*)(base + r * WW);
            float4 b = *(const float4*)(base + r * WW + 4);
            x[0] = fabsf(a.x); x[1] = fabsf(a.y); x[2] = fabsf(a.z); x[3] = fabsf(a.w);
            x[4] = fabsf(b.x); x[5] = fabsf(b.y); x[6] = fabsf(b.z); x[7] = fabsf(b.w);
        } else {
#pragma unroll
            for (int k = 0; k < 8; ++k) x[k] = 0.0f;
        }

        // horizontal halo from neighbor lanes (same row-unit): left lane's x6,x7;
        // right lane's x0,x1. Zero at unit edges.
        float l6 = __shfl_up(x[6], 1, 64);
        float l7 = __shfl_up(x[7], 1, 64);
        float r0 = __shfl_down(x[0], 1, 64);
        float r1 = __shfl_down(x[1], 1, 64);
        float e[12];
        e[0] = hl ? l6 : 0.0f;
        e[1] = hl ? l7 : 0.0f;
#pragma unroll
        for (int k = 0; k < 8; ++k) e[k + 2] = x[k];
        e[10] = hr ? r0 : 0.0f;
        e[11] = hr ? r1 : 0.0f;

        // pairwise-CSE horizontal 5-sums: h[j] = e[j]+e[j+1]+e[j+2]+e[j+3]+e[j+4]
        float p[11];
#pragma unroll
        for (int k = 0; k < 11; ++k) p[k] = e[k] + e[k + 1];
#pragma unroll
        for (int j = 0; j < 8; ++j) {
            rs[i % 5][j] = p[j] + p[j + 2] + e[j + 4];
            av[i % 3][j] = x[j];
        }

        if (i >= 4) {
#pragma unroll
            for (int j = 0; j < 8; ++j) {
                float box = rs[0][j] + rs[1][j] + rs[2][j] + rs[3][j] + rs[4][j];
                float a = av[(i - 2) % 3][j];
                acc += a * (box - a);
            }
        }
    }

    if (!active) acc = 0.0f;

    // ---- block reduction -> plain store (NO atomics) ----
#pragma unroll
    for (int off = 32; off > 0; off >>= 1) acc += __shfl_down(acc, off, 64);
    __shared__ float red[4];
    if (lane == 0) red[wid] = acc;
    __syncthreads();
    if (tid == 0) {
        ws[blockIdx.x] = red[0] + red[1] + red[2] + red[3];
    }
}

__global__ __launch_bounds__(256) void sdl_finish(const float* __restrict__ ws,
                                                  float* __restrict__ out) {
    const int tid = threadIdx.x;
    float acc = 0.0f;
#pragma unroll
    for (int k = 0; k < NBLOCKS / 256; ++k) acc += ws[tid + 256 * k];
#pragma unroll
    for (int off = 32; off > 0; off >>= 1) acc += __shfl_down(acc, off, 64);
    __shared__ float red[4];
    const int lane = tid & 63;
    const int wid  = tid >> 6;
    if (lane == 0) red[wid] = acc;
    __syncthreads();
    if (tid == 0) {
        out[0] = (red[0] + red[1] + red[2] + red[3]) * SCALE;
    }
}

extern "C" void kernel_launch(void* const* d_in, const int* in_sizes, int n_in,
                              void* d_out, int out_size, void* d_ws, size_t ws_size,
                              hipStream_t stream) {
    const float* y = (const float*)d_in[0];
    float* ws = (float*)d_ws;
    float* out = (float*)d_out;
    sdl_partial<<<NBLOCKS, 256, 0, stream>>>(y, ws);
    sdl_finish<<<1, 256, 0, stream>>>(ws, out);
}

// Round 7
// 146.254 us; speedup vs baseline: 1.1948x; 1.1948x over previous
//
#include <hip/hip_runtime.h>

// SpatialDistangleLoss: loss = sum_p |y_p| * (box5x5(|y|)_p - |y_p|) / 25 / (H*W*B)
// y shape (8, 320, 96, 96) fp32 -> 2560 planes of 96x96.
//
// R7: R6's shfl-halo register-ring structure, minus the register spill.
// R6's __launch_bounds__(256,4) clamped VGPRs to 64 while ~95 floats are live
// -> 92MB of scratch spill traffic (WRITE_SIZE counter) = the 79us. Fix: let
// the allocator pick (~130-160 VGPR, still >=2 blocks/CU). Strips widened to
// 16 rows (halo amp 1.25x, 768 blocks = exactly 3/CU).
// Each lane: 8 cols x 16 output rows, own 32B/row coalesced loads, horizontal
// halo via __shfl from neighbor lanes (no LDS, no barrier), vertical via
// register rings. Reduction: per-block plain store + tiny finish kernel.

#define HH 96
#define WW 96
#define NPLANES 2560
#define RSTRIP 16
#define STRIPS (HH / RSTRIP)      // 6
#define UNITS (NPLANES * STRIPS)  // 15360 (plane,strip) work units
#define UPW 5                     // units per wave (12 lanes each, 60/64 lanes)
#define NWAVES (UNITS / UPW)      // 3072
#define NBLOCKS (NWAVES / 4)      // 768 blocks of 256 = 3 blocks/CU
#define SCALE (1.0f / (25.0f * 96.0f * 96.0f * 8.0f))

__global__ __launch_bounds__(256) void sdl_partial(const float* __restrict__ y,
                                                   float* __restrict__ ws) {
    const int tid  = threadIdx.x;
    const int lane = tid & 63;
    const int wid  = tid >> 6;
    const int wgid = blockIdx.x * 4 + wid;

    const int sub = lane / 12;   // 0..4 active, 5 = idle (lanes 60..63)
    const int c8  = lane % 12;   // col-group of 8: cols c8*8 .. c8*8+7
    const bool active = (sub < UPW);
    const int unit  = wgid * UPW + (active ? sub : 0);  // clamp idle lanes to a valid unit
    const int plane = unit / STRIPS;
    const int strip = unit % STRIPS;
    const int row0  = strip * RSTRIP;

    const float* base = y + (size_t)plane * (HH * WW) + c8 * 8;
    const bool hl = (c8 > 0);
    const bool hr = (c8 < 11);

    float rs[5][8];  // ring: horizontal 5-sums for the last 5 loaded rows
    float av[3][8];  // ring: center |y| for the last 3 loaded rows
#pragma unroll
    for (int k = 0; k < 5; ++k)
#pragma unroll
        for (int j = 0; j < 8; ++j) rs[k][j] = 0.0f;
#pragma unroll
    for (int k = 0; k < 3; ++k)
#pragma unroll
        for (int j = 0; j < 8; ++j) av[k][j] = 0.0f;

    float acc = 0.0f;

#pragma unroll
    for (int i = 0; i < RSTRIP + 4; ++i) {
        const int r = row0 - 2 + i;  // row being loaded
        float x[8];
        if ((unsigned)r < (unsigned)HH) {
            float4 a = *(const float4*)(base + r * WW);
            float4 b = *(const float4*)(base + r * WW + 4);
            x[0] = fabsf(a.x); x[1] = fabsf(a.y); x[2] = fabsf(a.z); x[3] = fabsf(a.w);
            x[4] = fabsf(b.x); x[5] = fabsf(b.y); x[6] = fabsf(b.z); x[7] = fabsf(b.w);
        } else {
#pragma unroll
            for (int k = 0; k < 8; ++k) x[k] = 0.0f;
        }

        // horizontal halo from neighbor lanes (same row-unit): left lane's x6,x7;
        // right lane's x0,x1. Zero at unit edges.
        float l6 = __shfl_up(x[6], 1, 64);
        float l7 = __shfl_up(x[7], 1, 64);
        float r0 = __shfl_down(x[0], 1, 64);
        float r1 = __shfl_down(x[1], 1, 64);
        float e[12];
        e[0] = hl ? l6 : 0.0f;
        e[1] = hl ? l7 : 0.0f;
#pragma unroll
        for (int k = 0; k < 8; ++k) e[k + 2] = x[k];
        e[10] = hr ? r0 : 0.0f;
        e[11] = hr ? r1 : 0.0f;

        // pairwise-CSE horizontal 5-sums: h[j] = e[j]+e[j+1]+e[j+2]+e[j+3]+e[j+4]
        float p[11];
#pragma unroll
        for (int k = 0; k < 11; ++k) p[k] = e[k] + e[k + 1];
#pragma unroll
        for (int j = 0; j < 8; ++j) {
            rs[i % 5][j] = p[j] + p[j + 2] + e[j + 4];
            av[i % 3][j] = x[j];
        }

        if (i >= 4) {
#pragma unroll
            for (int j = 0; j < 8; ++j) {
                float box = rs[0][j] + rs[1][j] + rs[2][j] + rs[3][j] + rs[4][j];
                float a = av[(i - 2) % 3][j];
                acc += a * (box - a);
            }
        }
    }

    if (!active) acc = 0.0f;

    // ---- block reduction -> plain store (NO atomics) ----
#pragma unroll
    for (int off = 32; off > 0; off >>= 1) acc += __shfl_down(acc, off, 64);
    __shared__ float red[4];
    if (lane == 0) red[wid] = acc;
    __syncthreads();
    if (tid == 0) {
        ws[blockIdx.x] = red[0] + red[1] + red[2] + red[3];
    }
}

__global__ __launch_bounds__(256) void sdl_finish(const float* __restrict__ ws,
                                                  float* __restrict__ out) {
    const int tid = threadIdx.x;
    float acc = 0.0f;
#pragma unroll
    for (int k = 0; k < NBLOCKS / 256; ++k) acc += ws[tid + 256 * k];
#pragma unroll
    for (int off = 32; off > 0; off >>= 1) acc += __shfl_down(acc, off, 64);
    __shared__ float red[4];
    const int lane = tid & 63;
    const int wid  = tid >> 6;
    if (lane == 0) red[wid] = acc;
    __syncthreads();
    if (tid == 0) {
        out[0] = (red[0] + red[1] + red[2] + red[3]) * SCALE;
    }
}

extern "C" void kernel_launch(void* const* d_in, const int* in_sizes, int n_in,
                              void* d_out, int out_size, void* d_ws, size_t ws_size,
                              hipStream_t stream) {
    const float* y = (const float*)d_in[0];
    float* ws = (float*)d_ws;
    float* out = (float*)d_out;
    sdl_partial<<<NBLOCKS, 256, 0, stream>>>(y, ws);
    sdl_finish<<<1, 256, 0, stream>>>(ws, out);
}

// Round 8
// 134.971 us; speedup vs baseline: 1.2946x; 1.0836x over previous
//
#include <hip/hip_runtime.h>

// SpatialDistangleLoss: loss = sum_p |y_p| * (box5x5(|y|)_p - |y_p|) / 25 / (H*W*B)
// y shape (8, 320, 96, 96) fp32 -> 2560 planes of 96x96.
//
// R8: LDS tile staged via __builtin_amdgcn_global_load_lds (async DMA, no VGPR
// round-trip, deep MLP: ~7 resident blocks x 21KB in flight per CU), plus
// sliding-window box sums (h_j = h_{j-1} - e_{j-2} + e_{j+3}; vertical running
// sum vb += h_new - h_old) cutting VALU from ~35 to ~14 ops/element.
// R3-R7 post-mortems: all prior variants ~40-50us = HBM(15) + VALU(14) +
// LDS(10) poorly overlapped. DMA staging requires unpadded stride-96 LDS; the
// compute reads are conflict-free per 16-lane phase (2 lanes/bank = free).
// Tile: 48 output rows, 56 staged (56*384B = 21 chunks of 1024B exactly).
// Reduction: per-block plain store + finish kernel (no same-address atomics).

#define HH 96
#define WW 96
#define NPLANES 2560
#define QR 48                        // output rows per block
#define SR 56                        // staged rows (mult of 8 -> SR*384 % 1024 == 0)
#define NBLOCKS (NPLANES * 2)        // 5120
#define PLANE_BYTES (HH * WW * 4)    // 36864
#define CHUNKS ((SR * WW * 4) / 1024)  // 21
#define SCALE (1.0f / (25.0f * 96.0f * 96.0f * 8.0f))

__device__ __forceinline__ void stage16(const float* gp, float* lp) {
    // CK-style: LDS dest is wave-uniform base + lane*16 (HW scatter).
    auto* lds = (__attribute__((address_space(3))) unsigned int*)lp;
    const auto* g = (const __attribute__((address_space(1))) unsigned int*)gp;
    __builtin_amdgcn_global_load_lds(g, lds, 16, 0, 0);
}

__global__ __launch_bounds__(256) void sdl_partial(const float* __restrict__ y,
                                                   float* __restrict__ ws) {
    __shared__ float s[SR * WW];  // 21504 B, stride 96 (required by DMA scatter)
    __shared__ float red[4];

    const int tid  = threadIdx.x;
    const int lane = tid & 63;
    const int wid  = tid >> 6;
    const int plane = blockIdx.x >> 1;
    const int r0    = (blockIdx.x & 1) * QR;
    const float* pb = y + (size_t)plane * (HH * WW);

    // ---- async-stage rows r0-2 .. r0+53 (clamped; garbage rows never read) ----
#pragma unroll
    for (int k = 0; k < 6; ++k) {
        const int c = wid + 4 * k;  // wave-uniform chunk id
        if (c < CHUNKS) {
            int po = (r0 - 2) * (WW * 4) + c * 1024 + lane * 16;  // byte offset in plane
            po = min(max(po, 0), PLANE_BYTES - 16);               // clamp inside plane
            stage16((const float*)((const char*)pb + po), s + c * 256);
        }
    }
    __syncthreads();  // compiler emits s_waitcnt vmcnt(0) before s_barrier

    // ---- compute: 192 threads = 24 col-groups(4) x 8 row-strips(6 rows) ----
    float acc = 0.0f;
    if (tid < 192) {
        const int gx = tid % 24;
        const int st = tid / 24;
        const int lbase = st * 6;
        const bool hl = (gx > 0);
        const bool hr = (gx < 23);

        float h5[5][4];   // ring of horizontal 5-sums (last 5 rows)
        float vb[4];      // running vertical sum of the ring
        float am3[3][4];  // ring of |center| values (last 3 rows)
#pragma unroll
        for (int k = 0; k < 5; ++k)
#pragma unroll
            for (int j = 0; j < 4; ++j) h5[k][j] = 0.0f;
#pragma unroll
        for (int j = 0; j < 4; ++j) vb[j] = 0.0f;
#pragma unroll
        for (int k = 0; k < 3; ++k)
#pragma unroll
            for (int j = 0; j < 4; ++j) am3[k][j] = 0.0f;

#pragma unroll
        for (int i = 0; i < 10; ++i) {
            const int ls = lbase + i;        // staged row index
            const int g  = r0 - 2 + ls;      // global row
            float e0, e1, e2, e3, e4, e5, e6, e7;
            if ((unsigned)g < (unsigned)HH) {
                const float* rp = s + ls * WW + gx * 4;
                float4 m  = *(const float4*)rp;
                float2 lv = hl ? *(const float2*)(rp - 2) : make_float2(0.0f, 0.0f);
                float2 rv = hr ? *(const float2*)(rp + 4) : make_float2(0.0f, 0.0f);
                e0 = fabsf(lv.x); e1 = fabsf(lv.y);
                e2 = fabsf(m.x);  e3 = fabsf(m.y);
                e4 = fabsf(m.z);  e5 = fabsf(m.w);
                e6 = fabsf(rv.x); e7 = fabsf(rv.y);
            } else {
                e0 = e1 = e2 = e3 = e4 = e5 = e6 = e7 = 0.0f;
            }

            // sliding horizontal 5-sums: h_j = sum(e[j..j+4])
            float h0 = ((e0 + e1) + (e2 + e3)) + e4;
            float h1 = (h0 - e0) + e5;
            float h2 = (h1 - e1) + e6;
            float h3 = (h2 - e2) + e7;

            // running vertical 5-sum via ring
            const int o = i % 5;
            vb[0] += h0 - h5[o][0]; h5[o][0] = h0;
            vb[1] += h1 - h5[o][1]; h5[o][1] = h1;
            vb[2] += h2 - h5[o][2]; h5[o][2] = h2;
            vb[3] += h3 - h5[o][3]; h5[o][3] = h3;

            // center |y| ring
            const int a3 = i % 3;
            am3[a3][0] = e2; am3[a3][1] = e3; am3[a3][2] = e4; am3[a3][3] = e5;

            if (i >= 4) {
                // vb now covers rows (i-4..i) centered at i-2
                const int cs = (i - 2) % 3;
#pragma unroll
                for (int j = 0; j < 4; ++j) {
                    float a = am3[cs][j];
                    acc = fmaf(a, vb[j] - a, acc);
                }
            }
        }
    }

    // ---- block reduction -> plain store (NO atomics) ----
#pragma unroll
    for (int off = 32; off > 0; off >>= 1) acc += __shfl_down(acc, off, 64);
    if (lane == 0) red[wid] = acc;
    __syncthreads();
    if (tid == 0) {
        ws[blockIdx.x] = red[0] + red[1] + red[2] + red[3];
    }
}

__global__ __launch_bounds__(256) void sdl_finish(const float* __restrict__ ws,
                                                  float* __restrict__ out) {
    const int tid = threadIdx.x;
    float acc = 0.0f;
#pragma unroll
    for (int k = 0; k < NBLOCKS / 256; ++k) acc += ws[tid + 256 * k];
#pragma unroll
    for (int off = 32; off > 0; off >>= 1) acc += __shfl_down(acc, off, 64);
    __shared__ float red[4];
    const int lane = tid & 63;
    const int wid  = tid >> 6;
    if (lane == 0) red[wid] = acc;
    __syncthreads();
    if (tid == 0) {
        out[0] = (red[0] + red[1] + red[2] + red[3]) * SCALE;
    }
}

extern "C" void kernel_launch(void* const* d_in, const int* in_sizes, int n_in,
                              void* d_out, int out_size, void* d_ws, size_t ws_size,
                              hipStream_t stream) {
    const float* y = (const float*)d_in[0];
    float* ws = (float*)d_ws;
    float* out = (float*)d_out;
    sdl_partial<<<NBLOCKS, 256, 0, stream>>>(y, ws);
    sdl_finish<<<1, 256, 0, stream>>>(ws, out);
}